// Round 1
// baseline (639.709 us; speedup 1.0000x reference)
//
#include <hip/hip_runtime.h>
#include <math.h>

// Problem: B=2, T=2048, C=768, H=12, D=64.
// Reference note: the ALiBi bias  slope*max(j-i,0)  is nonzero only where the
// causal mask then writes -inf, so it has NO effect on the output. We compute
// plain causal softmax attention.
//
// Outputs: y (B,T,C)=3,145,728 fp32  then att (B,H,T,T)=100,663,296 fp32.

#define LOG2E 1.4426950408889634f

typedef __attribute__((ext_vector_type(8))) short bf16x8;
typedef __attribute__((ext_vector_type(4))) float f32x4;

__device__ __forceinline__ unsigned short f2bf(float f) {
  unsigned int u = __builtin_bit_cast(unsigned int, f);
  u = (u + 0x7fffu + ((u >> 16) & 1u)) >> 16;
  return (unsigned short)u;
}

// ---------------- convert / transpose ----------------
__global__ void k_convert(const float* __restrict__ in, unsigned short* __restrict__ out, int n4) {
  int i = blockIdx.x * blockDim.x + threadIdx.x;
  int stride = gridDim.x * blockDim.x;
  for (; i < n4; i += stride) {
    float4 v = reinterpret_cast<const float4*>(in)[i];
    ushort4 o;
    o.x = f2bf(v.x); o.y = f2bf(v.y); o.z = f2bf(v.z); o.w = f2bf(v.w);
    reinterpret_cast<ushort4*>(out)[i] = o;
  }
}

// in: K x N row-major fp32  ->  out: N x K row-major bf16
__global__ void k_transpose(const float* __restrict__ in, unsigned short* __restrict__ out, int K, int N) {
  int idx = blockIdx.x * blockDim.x + threadIdx.x;
  if (idx >= K * N) return;
  int k = idx / N, n = idx - k * N;
  out[(size_t)n * K + k] = f2bf(in[idx]);
}

// ---------------- bf16 GEMM (128x128 tile, BK=64, 4 waves) ----------------
// A: MxK bf16 row-major. Bt: NxK bf16 row-major (pre-transposed weights).
// mode 0: qkv epilogue -> q,k in (B,H,T,D) bf16, v in (B,H,D,T) bf16, +bias
// mode 1: plain fp32 out MxN, +bias
__global__ __launch_bounds__(256) void k_gemm(
    const unsigned short* __restrict__ A,
    const unsigned short* __restrict__ Bt,
    const float* __restrict__ bias,
    int M, int N, int K, int mode,
    unsigned short* __restrict__ qb,
    unsigned short* __restrict__ kb,
    unsigned short* __restrict__ vb,
    float* __restrict__ yout)
{
  __shared__ __align__(16) unsigned short As[128 * 64];
  __shared__ __align__(16) unsigned short Bs[128 * 64];
  const int bm = blockIdx.x, bn = blockIdx.y;
  const int tid = threadIdx.x;
  const int lane = tid & 63, wid = tid >> 6;
  const int wr = wid >> 1, wc = wid & 1;
  const int lr = lane & 15, lg = lane >> 4;

  f32x4 acc[4][4] = {};

  for (int k0 = 0; k0 < K; k0 += 64) {
    __syncthreads();
#pragma unroll
    for (int i = 0; i < 4; ++i) {
      int c = tid + i * 256;
      int row = c >> 3, g = c & 7;
      int sw = ((g ^ (row & 7)) * 8);
      *reinterpret_cast<bf16x8*>(&As[row * 64 + sw]) =
          *reinterpret_cast<const bf16x8*>(&A[(size_t)(bm * 128 + row) * K + k0 + g * 8]);
      *reinterpret_cast<bf16x8*>(&Bs[row * 64 + sw]) =
          *reinterpret_cast<const bf16x8*>(&Bt[(size_t)(bn * 128 + row) * K + k0 + g * 8]);
    }
    __syncthreads();
#pragma unroll
    for (int kk = 0; kk < 2; ++kk) {
      const int g = kk * 4 + lg;
      bf16x8 af[4], bfrag[4];
#pragma unroll
      for (int f = 0; f < 4; ++f) {
        int ra = wr * 64 + f * 16 + lr;
        af[f] = *reinterpret_cast<const bf16x8*>(&As[ra * 64 + ((g ^ (ra & 7)) * 8)]);
        int rb = wc * 64 + f * 16 + lr;
        bfrag[f] = *reinterpret_cast<const bf16x8*>(&Bs[rb * 64 + ((g ^ (rb & 7)) * 8)]);
      }
#pragma unroll
      for (int fm = 0; fm < 4; ++fm)
#pragma unroll
        for (int fn = 0; fn < 4; ++fn)
          acc[fm][fn] = __builtin_amdgcn_mfma_f32_16x16x32_bf16(af[fm], bfrag[fn], acc[fm][fn], 0, 0, 0);
    }
  }

#pragma unroll
  for (int fm = 0; fm < 4; ++fm)
#pragma unroll
    for (int fn = 0; fn < 4; ++fn) {
      int col = bn * 128 + wc * 64 + fn * 16 + lr;
      float bi = bias[col];
#pragma unroll
      for (int r = 0; r < 4; ++r) {
        int rowm = bm * 128 + wr * 64 + fm * 16 + lg * 4 + r;
        float val = acc[fm][fn][r] + bi;
        if (mode == 0) {
          int which = col / 768;
          int c = col - which * 768;
          int h = c >> 6, d = c & 63;
          int b = rowm >> 11, t = rowm & 2047;
          size_t bh = (size_t)b * 12 + h;
          unsigned short uv = f2bf(val);
          if (which == 0)      qb[(bh * 2048 + t) * 64 + d] = uv;
          else if (which == 1) kb[(bh * 2048 + t) * 64 + d] = uv;
          else                 vb[(bh * 64 + d) * 2048 + t] = uv;  // v stored transposed
        } else {
          yout[(size_t)rowm * N + col] = val;
        }
      }
    }
}

// ---------------- fused causal attention ----------------
// grid (32 qtiles, 24 bh), 256 threads = 4 waves, each wave owns 16 q-rows.
// Writes att (fp32, full rows incl. zero upper triangle) and yh (bf16 B,T,C).
__global__ __launch_bounds__(256) void k_attn(
    const unsigned short* __restrict__ qb,
    const unsigned short* __restrict__ kb,
    const unsigned short* __restrict__ vb,
    float* __restrict__ att,
    unsigned short* __restrict__ yh)
{
  __shared__ __align__(16) unsigned short Ks[64 * 64];
  __shared__ __align__(16) unsigned short Vs[64 * 64];
  __shared__ __align__(16) unsigned short Ps[4][16 * 64];

  const int qt = blockIdx.x;   // 0..31
  const int bh = blockIdx.y;   // 0..23
  const int tid = threadIdx.x;
  const int lane = tid & 63, wid = tid >> 6;
  const int lr = lane & 15, lg = lane >> 4;

  const unsigned short* Qg = qb + ((size_t)bh * 2048 + qt * 64) * 64;
  const unsigned short* Kg = kb + (size_t)bh * 2048 * 64;
  const unsigned short* Vg = vb + (size_t)bh * 64 * 2048;
  float* attg = att + ((size_t)bh * 2048 + qt * 64) * 2048;

  // Q fragments stay in registers (reused across all k-tiles)
  bf16x8 qf[2];
#pragma unroll
  for (int kk = 0; kk < 2; ++kk)
    qf[kk] = *reinterpret_cast<const bf16x8*>(&Qg[(wid * 16 + lr) * 64 + kk * 32 + lg * 8]);

  const int qrow_l = wid * 16 + lg * 4;  // + r = local q row in 64-block

  float m_r[4], l_r[4];
#pragma unroll
  for (int r = 0; r < 4; ++r) { m_r[r] = -__builtin_inff(); l_r[r] = 0.f; }

  // ---- pass 1: row max m and denom l (online, scores discarded) ----
  for (int kt = 0; kt <= qt; ++kt) {
    __syncthreads();
#pragma unroll
    for (int i = 0; i < 2; ++i) {
      int c = tid + i * 256;
      int row = c >> 3, g = c & 7;
      *reinterpret_cast<bf16x8*>(&Ks[row * 64 + ((g ^ (row & 7)) * 8)]) =
          *reinterpret_cast<const bf16x8*>(&Kg[(kt * 64 + row) * 64 + g * 8]);
    }
    __syncthreads();

    f32x4 s[4] = {};
#pragma unroll
    for (int kk = 0; kk < 2; ++kk) {
      int g = kk * 4 + lg;
#pragma unroll
      for (int fc = 0; fc < 4; ++fc) {
        int row = fc * 16 + lr;
        bf16x8 kf = *reinterpret_cast<const bf16x8*>(&Ks[row * 64 + ((g ^ (row & 7)) * 8)]);
        s[fc] = __builtin_amdgcn_mfma_f32_16x16x32_bf16(qf[kk], kf, s[fc], 0, 0, 0);
      }
    }

#pragma unroll
    for (int r = 0; r < 4; ++r) {
      float sv[4];
      float mx = -__builtin_inff();
#pragma unroll
      for (int fc = 0; fc < 4; ++fc) {
        float x = s[fc][r] * 0.125f;
        if (kt == qt && (fc * 16 + lr) > (qrow_l + r)) x = -__builtin_inff();
        sv[fc] = x;
        mx = fmaxf(mx, x);
      }
#pragma unroll
      for (int d = 1; d < 16; d <<= 1) mx = fmaxf(mx, __shfl_xor(mx, d));
      float mnew = fmaxf(m_r[r], mx);
      float sum = 0.f;
#pragma unroll
      for (int fc = 0; fc < 4; ++fc) sum += exp2f((sv[fc] - mnew) * LOG2E);
#pragma unroll
      for (int d = 1; d < 16; d <<= 1) sum += __shfl_xor(sum, d);
      l_r[r] = l_r[r] * exp2f((m_r[r] - mnew) * LOG2E) + sum;
      m_r[r] = mnew;
    }
  }

  float rcp_l[4];
#pragma unroll
  for (int r = 0; r < 4; ++r) rcp_l[r] = 1.0f / l_r[r];

  // ---- pass 2: recompute S, write att, accumulate O = P·V ----
  f32x4 o[4] = {};
  for (int kt = 0; kt <= qt; ++kt) {
    __syncthreads();
#pragma unroll
    for (int i = 0; i < 2; ++i) {
      int c = tid + i * 256;
      int row = c >> 3, g = c & 7;
      *reinterpret_cast<bf16x8*>(&Ks[row * 64 + ((g ^ (row & 7)) * 8)]) =
          *reinterpret_cast<const bf16x8*>(&Kg[(kt * 64 + row) * 64 + g * 8]);
      *reinterpret_cast<bf16x8*>(&Vs[row * 64 + ((g ^ (row & 7)) * 8)]) =
          *reinterpret_cast<const bf16x8*>(&Vg[(size_t)row * 2048 + kt * 64 + g * 8]);
    }
    __syncthreads();

    f32x4 s[4] = {};
#pragma unroll
    for (int kk = 0; kk < 2; ++kk) {
      int g = kk * 4 + lg;
#pragma unroll
      for (int fc = 0; fc < 4; ++fc) {
        int row = fc * 16 + lr;
        bf16x8 kf = *reinterpret_cast<const bf16x8*>(&Ks[row * 64 + ((g ^ (row & 7)) * 8)]);
        s[fc] = __builtin_amdgcn_mfma_f32_16x16x32_bf16(qf[kk], kf, s[fc], 0, 0, 0);
      }
    }

#pragma unroll
    for (int fc = 0; fc < 4; ++fc)
#pragma unroll
      for (int r = 0; r < 4; ++r) {
        float x = s[fc][r] * 0.125f;
        bool masked = (kt == qt) && ((fc * 16 + lr) > (qrow_l + r));
        float p = masked ? 0.f : exp2f((x - m_r[r]) * LOG2E);
        attg[(size_t)(qrow_l + r) * 2048 + kt * 64 + fc * 16 + lr] = p * rcp_l[r];
        int pr = lg * 4 + r;             // row within this wave's 16-row P tile
        int col = fc * 16 + lr;
        Ps[wid][pr * 64 + (((col >> 3) ^ (pr & 7)) * 8) + (col & 7)] = f2bf(p);
      }

    __syncthreads();

#pragma unroll
    for (int kk = 0; kk < 2; ++kk) {
      int g = kk * 4 + lg;
      bf16x8 pa = *reinterpret_cast<const bf16x8*>(&Ps[wid][lr * 64 + ((g ^ (lr & 7)) * 8)]);
#pragma unroll
      for (int fc = 0; fc < 4; ++fc) {
        int row = fc * 16 + lr;
        bf16x8 vf = *reinterpret_cast<const bf16x8*>(&Vs[row * 64 + ((g ^ (row & 7)) * 8)]);
        o[fc] = __builtin_amdgcn_mfma_f32_16x16x32_bf16(pa, vf, o[fc], 0, 0, 0);
      }
    }
  }

  // ---- zero-fill strict upper triangle tiles (harness poisons d_out) ----
  {
    int W = 2048 - (qt + 1) * 64;
    if (W > 0) {
      int base = (qt + 1) * 64;
      int Wq = W >> 2;
      int n4 = 64 * Wq;
      float4 z = {0.f, 0.f, 0.f, 0.f};
      for (int i = tid; i < n4; i += 256) {
        int row = i / Wq, c4 = i - row * Wq;
        *reinterpret_cast<float4*>(&attg[(size_t)row * 2048 + base + c4 * 4]) = z;
      }
    }
  }

  // ---- epilogue: O/l -> yh (B,T,C) bf16 ----
  {
    int b = bh / 12, h = bh - b * 12;
#pragma unroll
    for (int fc = 0; fc < 4; ++fc)
#pragma unroll
      for (int r = 0; r < 4; ++r) {
        int tg = qt * 64 + qrow_l + r;
        yh[((size_t)b * 2048 + tg) * 768 + h * 64 + fc * 16 + lr] = f2bf(o[fc][r] * rcp_l[r]);
      }
  }
}

// ---------------- launcher ----------------
extern "C" void kernel_launch(void* const* d_in, const int* in_sizes, int n_in,
                              void* d_out, int out_size, void* d_ws, size_t ws_size,
                              hipStream_t stream) {
  const float* x     = (const float*)d_in[0];
  const float* Wqkv  = (const float*)d_in[1];
  const float* bqkv  = (const float*)d_in[2];
  const float* Wproj = (const float*)d_in[3];
  const float* bproj = (const float*)d_in[4];

  float* y   = (float*)d_out;
  float* att = y + (size_t)2 * 2048 * 768;

  char* ws = (char*)d_ws;
  unsigned short* xb     = (unsigned short*)(ws);             // 4096x768 bf16
  unsigned short* wqkvT  = (unsigned short*)(ws + 6291456);   // 2304x768 bf16
  unsigned short* wprojT = (unsigned short*)(ws + 9830400);   // 768x768 bf16
  unsigned short* qb     = (unsigned short*)(ws + 11010048);  // (B,H,T,D) bf16
  unsigned short* kb     = (unsigned short*)(ws + 17301504);  // (B,H,T,D) bf16
  unsigned short* vb     = (unsigned short*)(ws + 23592960);  // (B,H,D,T) bf16
  unsigned short* yh     = (unsigned short*)(ws + 29884416);  // (B,T,C) bf16

  k_convert<<<1024, 256, 0, stream>>>(x, xb, (2 * 2048 * 768) / 4);
  k_transpose<<<(768 * 2304 + 255) / 256, 256, 0, stream>>>(Wqkv, wqkvT, 768, 2304);
  k_transpose<<<(768 * 768 + 255) / 256, 256, 0, stream>>>(Wproj, wprojT, 768, 768);

  k_gemm<<<dim3(32, 18), 256, 0, stream>>>(xb, wqkvT, bqkv, 4096, 2304, 768, 0,
                                           qb, kb, vb, nullptr);
  k_attn<<<dim3(32, 24), 256, 0, stream>>>(qb, kb, vb, att, yh);
  k_gemm<<<dim3(32, 6), 256, 0, stream>>>(yh, wprojT, bproj, 4096, 768, 768, 1,
                                          nullptr, nullptr, nullptr, y);
}